// Round 1
// baseline (841.187 us; speedup 1.0000x reference)
//
#include <hip/hip_runtime.h>
#include <hip/hip_bf16.h>
#include <cstdint>
#include <cstddef>

// ---------------------------------------------------------------------------
// TensoSDF shape renderer: tri-plane sample + embed -> MLP(129->256->129)
// Strategy: channel-last f16 transposed planes for vector sampling,
// f16 MFMA (16x16x32) MLP with fp32 accumulate, fused per-64-point-tile.
// ---------------------------------------------------------------------------

using half4  = __attribute__((ext_vector_type(4))) _Float16;
using half8  = __attribute__((ext_vector_type(8))) _Float16;
using floatx4 = __attribute__((ext_vector_type(4))) float;

#define NPTS    524288
#define GRES    300
#define NCOMP   36
#define SDFD    256
#define IN_CH   129     // 21 embed + 108 feat
#define IN_PAD  160     // 5 K-steps of 32
#define OUT_CH  129
#define OUT_PAD 144     // 9 N-tiles of 16
#define TILE_M  64
#define S_IN    168     // LDS stride for mlp_in tile (+8 pad -> only 2-way bank alias)
#define S_H     264     // LDS stride for h tile

// workspace layout (bytes), all 16B aligned
#define OFF_W1S 0
#define SZ_W1S  (5*4*256*8*2)          // 81920   : w1 swizzled f16 [s][quad][n=256][j=8]
#define OFF_W2S (OFF_W1S + SZ_W1S)
#define SZ_W2S  (8*4*144*8*2)          // 73728   : w2 swizzled f16 [s][quad][n=144][j=8]
#define OFF_PLT (OFF_W2S + SZ_W2S)
#define SZ_PLT  (3*300*300*36*2)       // 19440000: planes channel-last f16
#define OFF_LT  (OFF_PLT + SZ_PLT)
#define SZ_LT   (3*300*36*2)           // 64800   : lines channel-last f16
#define WS_NEED_FAST ((size_t)(OFF_LT + SZ_LT))

// input-dim permutation: new k in [0,108) = feat (orig 21+k); [108,129) = embed (orig k-108)

// ---- prep kernels ---------------------------------------------------------

__global__ void prep_planes_k(const float* __restrict__ planes, _Float16* __restrict__ pl_t) {
    int idx = blockIdx.x * 256 + threadIdx.x;           // (m*300+y)*300+x
    if (idx >= 3 * GRES * GRES) return;
    int x = idx % GRES; int t = idx / GRES; int y = t % GRES; int m = t / GRES;
    _Float16* dst = pl_t + (size_t)idx * NCOMP;
    const float* src = planes + (size_t)m * NCOMP * GRES * GRES + (size_t)y * GRES + x;
    #pragma unroll 4
    for (int c = 0; c < NCOMP; ++c)
        dst[c] = (_Float16)src[(size_t)c * GRES * GRES];   // coalesced across lanes per c
}

__global__ void prep_lines_k(const float* __restrict__ lines, _Float16* __restrict__ l_t) {
    int idx = blockIdx.x * 256 + threadIdx.x;           // m*300+z
    if (idx >= 3 * GRES) return;
    int z = idx % GRES; int m = idx / GRES;
    _Float16* dst = l_t + (size_t)idx * NCOMP;
    const float* src = lines + ((size_t)m * NCOMP) * GRES + z;
    for (int c = 0; c < NCOMP; ++c)
        dst[c] = (_Float16)src[(size_t)c * GRES];
}

// w1s flat index = ((s*4+quad)*256 + n)*8 + j ; value = w1[n][k_orig], k = s*32+quad*8+j
__global__ void prep_w1_k(const float* __restrict__ w1, _Float16* __restrict__ w1s) {
    int t = blockIdx.x * 256 + threadIdx.x;
    if (t >= 5 * 4 * 256 * 8) return;
    int j = t & 7; int n = (t >> 3) & 255; int q = t >> 11;          // q = s*4+quad, 0..19
    int k = (q >> 2) * 32 + (q & 3) * 8 + j;                          // 0..159
    float v = 0.f;
    if (k < IN_CH) {
        int ko = (k < 108) ? (21 + k) : (k - 108);                    // permutation
        v = w1[n * IN_CH + ko];
    }
    w1s[t] = (_Float16)v;
}

// w2s flat index = ((s*4+quad)*144 + n)*8 + j ; value = w2[n][k], k = s*32+quad*8+j
__global__ void prep_w2_k(const float* __restrict__ w2, _Float16* __restrict__ w2s) {
    int t = blockIdx.x * 256 + threadIdx.x;
    if (t >= 8 * 4 * 144 * 8) return;
    int j = t & 7; int r = t >> 3; int n = r % 144; int q = r / 144;  // q = s*4+quad, 0..31
    int k = (q >> 2) * 32 + (q & 3) * 8 + j;                          // 0..255
    float v = (n < OUT_CH) ? w2[n * SDFD + k] : 0.f;
    w2s[t] = (_Float16)v;
}

// ---- fused kernel ---------------------------------------------------------

template <bool FAST>
__global__ __launch_bounds__(256, 2)
void tsdf_fused_k(const float* __restrict__ xyz,
                  const float* __restrict__ planes,
                  const float* __restrict__ lines,
                  const _Float16* __restrict__ pl_t,
                  const _Float16* __restrict__ l_t,
                  const _Float16* __restrict__ w1s,
                  const _Float16* __restrict__ w2s,
                  const float* __restrict__ b1,
                  const float* __restrict__ b2,
                  float* __restrict__ out)
{
    __shared__ _Float16 mlp_lds[TILE_M * S_IN];   // 21504 B
    __shared__ _Float16 h_lds[TILE_M * S_H];      // 33792 B
    const int tid = threadIdx.x;
    const int blk = blockIdx.x;

    // ---------------- phase 1: sampling + embed into LDS -------------------
    {
        const int p   = tid >> 2;     // point within tile
        const int sub = tid & 3;      // 0..2 = plane mode, 3 = embed+pad
        const size_t gp = (size_t)blk * TILE_M + p;
        const float X = xyz[gp * 3 + 0];
        const float Y = xyz[gp * 3 + 1];
        const float Z = xyz[gp * 3 + 2];
        if (sub < 3) {
            const int m = sub;
            const float px = (m == 2) ? Y : X;
            const float py = (m == 0) ? Y : Z;
            const float pz = (m == 0) ? Z : ((m == 1) ? Y : X);
            float fx = (px + 1.f) * 0.5f * 299.f;
            float fy = (py + 1.f) * 0.5f * 299.f;
            float fz = (pz + 1.f) * 0.5f * 299.f;
            int x0 = (int)floorf(fx); x0 = x0 < 0 ? 0 : (x0 > 298 ? 298 : x0);
            int y0 = (int)floorf(fy); y0 = y0 < 0 ? 0 : (y0 > 298 ? 298 : y0);
            int z0 = (int)floorf(fz); z0 = z0 < 0 ? 0 : (z0 > 298 ? 298 : z0);
            const float tx = fx - (float)x0, ty = fy - (float)y0, tz = fz - (float)z0;
            const float w00 = (1.f - tx) * (1.f - ty), w01 = tx * (1.f - ty);
            const float w10 = (1.f - tx) * ty,         w11 = tx * ty;
            const float lw0 = 1.f - tz, lw1 = tz;
            _Float16* dst = &mlp_lds[p * S_IN + m * NCOMP];
            if (FAST) {
                const _Float16* b00 = pl_t + ((size_t)(m * GRES + y0) * GRES + x0) * NCOMP;
                const _Float16* lb  = l_t + (size_t)(m * GRES + z0) * NCOMP;
                #pragma unroll
                for (int c = 0; c < NCOMP; c += 4) {
                    half4 v00 = *(const half4*)(b00 + c);
                    half4 v01 = *(const half4*)(b00 + NCOMP + c);
                    half4 v10 = *(const half4*)(b00 + GRES * NCOMP + c);
                    half4 v11 = *(const half4*)(b00 + GRES * NCOMP + NCOMP + c);
                    half4 l0  = *(const half4*)(lb + c);
                    half4 l1  = *(const half4*)(lb + NCOMP + c);
                    half4 o;
                    #pragma unroll
                    for (int i = 0; i < 4; ++i) {
                        float pf = (float)v00[i] * w00 + (float)v01[i] * w01
                                 + (float)v10[i] * w10 + (float)v11[i] * w11;
                        float lf = (float)l0[i] * lw0 + (float)l1[i] * lw1;
                        o[i] = (_Float16)(pf * lf);
                    }
                    *(half4*)(dst + c) = o;
                }
            } else {
                // fallback: sample original fp32 layout (slow, correct)
                const float* pb = planes + (size_t)m * NCOMP * GRES * GRES;
                for (int c = 0; c < NCOMP; ++c) {
                    const float* pc = pb + (size_t)c * GRES * GRES + (size_t)y0 * GRES + x0;
                    const float* lc = lines + ((size_t)m * NCOMP + c) * GRES + z0;
                    float pf = pc[0] * w00 + pc[1] * w01 + pc[GRES] * w10 + pc[GRES + 1] * w11;
                    float lf = lc[0] * lw0 + lc[1] * lw1;
                    dst[c] = (_Float16)(pf * lf);
                }
            }
        } else {
            // embed: new k 108..110 = xyz; 111+d*3+f = sin(x_d*2^f); 120+d*3+f = cos
            _Float16* e = &mlp_lds[p * S_IN];
            e[108] = (_Float16)X; e[109] = (_Float16)Y; e[110] = (_Float16)Z;
            const float v3[3] = {X, Y, Z};
            #pragma unroll
            for (int d = 0; d < 3; ++d) {
                float f = 1.f;
                #pragma unroll
                for (int q = 0; q < 3; ++q) {
                    const float a = v3[d] * f;
                    e[111 + d * 3 + q] = (_Float16)__sinf(a);
                    e[120 + d * 3 + q] = (_Float16)__cosf(a);
                    f *= 2.f;
                }
            }
            for (int k = IN_CH; k < IN_PAD; ++k) e[k] = (_Float16)0.f;  // MUST zero pad
        }
    }
    __syncthreads();

    const int lane = tid & 63;
    const int wv   = tid >> 6;      // wave 0..3
    const int l15  = lane & 15;
    const int quad = lane >> 4;

    // ---------------- layer 1: [64x160] @ [160x256] -> h -------------------
    // wave wv owns N range [wv*64, wv*64+64)
    floatx4 acc1[4][4];
    #pragma unroll
    for (int mt = 0; mt < 4; ++mt)
        #pragma unroll
        for (int nt = 0; nt < 4; ++nt)
            acc1[mt][nt] = (floatx4){0.f, 0.f, 0.f, 0.f};

    #pragma unroll
    for (int s = 0; s < 5; ++s) {
        half8 a[4], b[4];
        #pragma unroll
        for (int mt = 0; mt < 4; ++mt)
            a[mt] = *(const half8*)&mlp_lds[(mt * 16 + l15) * S_IN + s * 32 + quad * 8];
        #pragma unroll
        for (int nt = 0; nt < 4; ++nt)
            b[nt] = *(const half8*)&w1s[((size_t)(s * 4 + quad) * 256 + wv * 64 + nt * 16 + l15) * 8];
        #pragma unroll
        for (int mt = 0; mt < 4; ++mt)
            #pragma unroll
            for (int nt = 0; nt < 4; ++nt)
                acc1[mt][nt] = __builtin_amdgcn_mfma_f32_16x16x32_f16(a[mt], b[nt], acc1[mt][nt], 0, 0, 0);
    }
    // epilogue: softplus(100z)/100, write h (f16) to LDS in [m][k] layout
    #pragma unroll
    for (int nt = 0; nt < 4; ++nt) {
        const int n = wv * 64 + nt * 16 + l15;
        const float bias = b1[n];
        #pragma unroll
        for (int mt = 0; mt < 4; ++mt) {
            #pragma unroll
            for (int r = 0; r < 4; ++r) {
                const float z  = 100.f * (acc1[mt][nt][r] + bias);
                const float sp = fmaxf(z, 0.f) + log1pf(__expf(-fabsf(z)));
                h_lds[(mt * 16 + quad * 4 + r) * S_H + n] = (_Float16)(sp * 0.01f);
            }
        }
    }
    __syncthreads();

    // ---------------- layer 2: [64x256] @ [256x144] -> out -----------------
    // wave wv owns M-tile wv (rows wv*16..wv*16+15)
    floatx4 acc2[9];
    #pragma unroll
    for (int nt = 0; nt < 9; ++nt) acc2[nt] = (floatx4){0.f, 0.f, 0.f, 0.f};

    #pragma unroll
    for (int s = 0; s < 8; ++s) {
        const half8 a = *(const half8*)&h_lds[(wv * 16 + l15) * S_H + s * 32 + quad * 8];
        #pragma unroll
        for (int nt = 0; nt < 9; ++nt) {
            const half8 b = *(const half8*)&w2s[((size_t)(s * 4 + quad) * 144 + nt * 16 + l15) * 8];
            acc2[nt] = __builtin_amdgcn_mfma_f32_16x16x32_f16(a, b, acc2[nt], 0, 0, 0);
        }
    }
    const int m_lo = wv * 16 + quad * 4;
    #pragma unroll
    for (int nt = 0; nt < 9; ++nt) {
        const int n = nt * 16 + l15;
        if (n < OUT_CH) {
            const float bias = b2[n];
            #pragma unroll
            for (int r = 0; r < 4; ++r) {
                const size_t gm = (size_t)blk * TILE_M + m_lo + r;
                out[gm * OUT_CH + n] = acc2[nt][r] + bias;
            }
        }
    }
}

// ---- launch ---------------------------------------------------------------

extern "C" void kernel_launch(void* const* d_in, const int* in_sizes, int n_in,
                              void* d_out, int out_size, void* d_ws, size_t ws_size,
                              hipStream_t stream) {
    const float* xyz    = (const float*)d_in[0];
    const float* planes = (const float*)d_in[1];
    const float* lines  = (const float*)d_in[2];
    const float* w1     = (const float*)d_in[3];
    const float* b1     = (const float*)d_in[4];
    const float* w2     = (const float*)d_in[5];
    const float* b2     = (const float*)d_in[6];
    float* out = (float*)d_out;
    char* ws = (char*)d_ws;

    _Float16* w1s  = (_Float16*)(ws + OFF_W1S);
    _Float16* w2s  = (_Float16*)(ws + OFF_W2S);
    _Float16* pl_t = (_Float16*)(ws + OFF_PLT);
    _Float16* l_t  = (_Float16*)(ws + OFF_LT);

    const bool fast = (ws_size >= WS_NEED_FAST);

    prep_w1_k<<<(5 * 4 * 256 * 8 + 255) / 256, 256, 0, stream>>>(w1, w1s);
    prep_w2_k<<<(8 * 4 * 144 * 8 + 255) / 256, 256, 0, stream>>>(w2, w2s);

    if (fast) {
        prep_planes_k<<<(3 * GRES * GRES + 255) / 256, 256, 0, stream>>>(planes, pl_t);
        prep_lines_k<<<(3 * GRES + 255) / 256, 256, 0, stream>>>(lines, l_t);
        tsdf_fused_k<true><<<NPTS / TILE_M, 256, 0, stream>>>(
            xyz, planes, lines, pl_t, l_t, w1s, w2s, b1, b2, out);
    } else {
        tsdf_fused_k<false><<<NPTS / TILE_M, 256, 0, stream>>>(
            xyz, planes, lines, pl_t, l_t, w1s, w2s, b1, b2, out);
    }
}

// Round 2
// 581.363 us; speedup vs baseline: 1.4469x; 1.4469x over previous
//
#include <hip/hip_runtime.h>
#include <hip/hip_bf16.h>
#include <cstdint>
#include <cstddef>

// ---------------------------------------------------------------------------
// TensoSDF shape renderer: tri-plane sample + embed -> MLP(129->256->129)
// R1: fast softplus (v_exp/v_log), packed-f16 interpolation, merged preps.
// ---------------------------------------------------------------------------

using half2v = __attribute__((ext_vector_type(2))) _Float16;
using half4  = __attribute__((ext_vector_type(4))) _Float16;
using half8  = __attribute__((ext_vector_type(8))) _Float16;
using floatx4 = __attribute__((ext_vector_type(4))) float;

#define NPTS    524288
#define GRES    300
#define NCOMP   36
#define SDFD    256
#define IN_CH   129     // 21 embed + 108 feat (k-permuted: feat first)
#define IN_PAD  160     // 5 K-steps of 32
#define OUT_CH  129
#define OUT_PAD 144     // 9 N-tiles of 16
#define TILE_M  64
#define S_IN    168     // LDS stride for mlp_in tile
#define S_H     264     // LDS stride for h tile

// workspace layout (bytes), all 16B aligned
#define OFF_W1S 0
#define SZ_W1S  (5*4*256*8*2)          // 81920   : w1 swizzled f16 [s][quad][n=256][j=8]
#define OFF_W2S (OFF_W1S + SZ_W1S)
#define SZ_W2S  (8*4*144*8*2)          // 73728   : w2 swizzled f16 [s][quad][n=144][j=8]
#define OFF_PLT (OFF_W2S + SZ_W2S)
#define SZ_PLT  (3*300*300*36*2)       // 19440000: planes channel-last f16
#define OFF_LT  (OFF_PLT + SZ_PLT)
#define SZ_LT   (3*300*36*2)           // 64800   : lines channel-last f16
#define WS_NEED_FAST ((size_t)(OFF_LT + SZ_LT))

// ---- prep kernels ---------------------------------------------------------

__global__ void prep_planes_k(const float* __restrict__ planes, _Float16* __restrict__ pl_t) {
    int idx = blockIdx.x * 256 + threadIdx.x;           // (m*300+y)*300+x
    if (idx >= 3 * GRES * GRES) return;
    int x = idx % GRES; int t = idx / GRES; int y = t % GRES; int m = t / GRES;
    _Float16* dst = pl_t + (size_t)idx * NCOMP;
    const float* src = planes + (size_t)m * NCOMP * GRES * GRES + (size_t)y * GRES + x;
    // gather 36 channels (coalesced across lanes per c), store as 9 half4
    #pragma unroll
    for (int c4 = 0; c4 < NCOMP; c4 += 4) {
        half4 o;
        #pragma unroll
        for (int i = 0; i < 4; ++i)
            o[i] = (_Float16)src[(size_t)(c4 + i) * GRES * GRES];
        *(half4*)(dst + c4) = o;
    }
}

// small preps merged: blocks [0, NB_W1) -> w1s, [NB_W1, NB_W1+NB_W2) -> w2s,
// [NB_W1+NB_W2, +NB_L) -> lines
#define NB_W1 ((5*4*256*8 + 255)/256)      // 160
#define NB_W2 ((8*4*144*8 + 255)/256)      // 144
#define NB_L  ((3*GRES + 255)/256)         // 4
__global__ void prep_small_k(const float* __restrict__ w1, const float* __restrict__ w2,
                             const float* __restrict__ lines,
                             _Float16* __restrict__ w1s, _Float16* __restrict__ w2s,
                             _Float16* __restrict__ l_t) {
    int b = blockIdx.x;
    if (b < NB_W1) {
        int t = b * 256 + threadIdx.x;
        if (t >= 5 * 4 * 256 * 8) return;
        int j = t & 7; int n = (t >> 3) & 255; int q = t >> 11;      // q = s*4+quad
        int k = (q >> 2) * 32 + (q & 3) * 8 + j;                      // 0..159
        float v = 0.f;
        if (k < IN_CH) {
            int ko = (k < 108) ? (21 + k) : (k - 108);                // permutation
            v = w1[n * IN_CH + ko];
        }
        w1s[t] = (_Float16)v;
    } else if (b < NB_W1 + NB_W2) {
        int t = (b - NB_W1) * 256 + threadIdx.x;
        if (t >= 8 * 4 * 144 * 8) return;
        int j = t & 7; int r = t >> 3; int n = r % 144; int q = r / 144;
        int k = (q >> 2) * 32 + (q & 3) * 8 + j;                      // 0..255
        float v = (n < OUT_CH) ? w2[n * SDFD + k] : 0.f;
        w2s[t] = (_Float16)v;
    } else {
        int idx = (b - NB_W1 - NB_W2) * 256 + threadIdx.x;            // m*300+z
        if (idx >= 3 * GRES) return;
        int z = idx % GRES; int m = idx / GRES;
        _Float16* dst = l_t + (size_t)idx * NCOMP;
        const float* src = lines + ((size_t)m * NCOMP) * GRES + z;
        for (int c = 0; c < NCOMP; ++c)
            dst[c] = (_Float16)src[(size_t)c * GRES];
    }
}

// ---- fused kernel ---------------------------------------------------------

__device__ __forceinline__ float softplus100(float z) {
    // softplus(z) with z pre-scaled by 100; caller multiplies by 0.01
    return fmaxf(z, 0.f) + __logf(1.f + __expf(-fabsf(z)));
}

template <bool FAST>
__global__ __launch_bounds__(256, 2)
void tsdf_fused_k(const float* __restrict__ xyz,
                  const float* __restrict__ planes,
                  const float* __restrict__ lines,
                  const _Float16* __restrict__ pl_t,
                  const _Float16* __restrict__ l_t,
                  const _Float16* __restrict__ w1s,
                  const _Float16* __restrict__ w2s,
                  const float* __restrict__ b1,
                  const float* __restrict__ b2,
                  float* __restrict__ out)
{
    __shared__ _Float16 mlp_lds[TILE_M * S_IN];   // 21504 B
    __shared__ _Float16 h_lds[TILE_M * S_H];      // 33792 B
    const int tid = threadIdx.x;
    const int blk = blockIdx.x;

    // ---------------- phase 1: sampling + embed into LDS -------------------
    {
        const int p   = tid >> 2;     // point within tile
        const int sub = tid & 3;      // 0..2 = plane mode, 3 = embed+pad
        const size_t gp = (size_t)blk * TILE_M + p;
        const float X = xyz[gp * 3 + 0];
        const float Y = xyz[gp * 3 + 1];
        const float Z = xyz[gp * 3 + 2];
        if (sub < 3) {
            const int m = sub;
            const float px = (m == 2) ? Y : X;
            const float py = (m == 0) ? Y : Z;
            const float pz = (m == 0) ? Z : ((m == 1) ? Y : X);
            float fx = (px + 1.f) * 0.5f * 299.f;
            float fy = (py + 1.f) * 0.5f * 299.f;
            float fz = (pz + 1.f) * 0.5f * 299.f;
            int x0 = (int)floorf(fx); x0 = x0 < 0 ? 0 : (x0 > 298 ? 298 : x0);
            int y0 = (int)floorf(fy); y0 = y0 < 0 ? 0 : (y0 > 298 ? 298 : y0);
            int z0 = (int)floorf(fz); z0 = z0 < 0 ? 0 : (z0 > 298 ? 298 : z0);
            const float tx = fx - (float)x0, ty = fy - (float)y0, tz = fz - (float)z0;
            const float w00 = (1.f - tx) * (1.f - ty), w01 = tx * (1.f - ty);
            const float w10 = (1.f - tx) * ty,         w11 = tx * ty;
            const float lw0 = 1.f - tz, lw1 = tz;
            _Float16* dst = &mlp_lds[p * S_IN + m * NCOMP];
            if (FAST) {
                // packed-f16 interpolation: v_pk_* ops, ~3.5 VALU/channel
                const _Float16 h00 = (_Float16)w00, h01 = (_Float16)w01;
                const _Float16 h10 = (_Float16)w10, h11 = (_Float16)w11;
                const _Float16 hl0 = (_Float16)lw0, hl1 = (_Float16)lw1;
                const half4 W00 = {h00, h00, h00, h00}, W01 = {h01, h01, h01, h01};
                const half4 W10 = {h10, h10, h10, h10}, W11 = {h11, h11, h11, h11};
                const half4 WL0 = {hl0, hl0, hl0, hl0}, WL1 = {hl1, hl1, hl1, hl1};
                const _Float16* b00 = pl_t + ((size_t)(m * GRES + y0) * GRES + x0) * NCOMP;
                const _Float16* lb  = l_t + (size_t)(m * GRES + z0) * NCOMP;
                #pragma unroll
                for (int c = 0; c < NCOMP; c += 4) {
                    half4 v00 = *(const half4*)(b00 + c);
                    half4 v01 = *(const half4*)(b00 + NCOMP + c);
                    half4 v10 = *(const half4*)(b00 + GRES * NCOMP + c);
                    half4 v11 = *(const half4*)(b00 + GRES * NCOMP + NCOMP + c);
                    half4 l0  = *(const half4*)(lb + c);
                    half4 l1  = *(const half4*)(lb + NCOMP + c);
                    half4 pf = v00 * W00 + v01 * W01 + v10 * W10 + v11 * W11;
                    half4 lf = l0 * WL0 + l1 * WL1;
                    *(half4*)(dst + c) = pf * lf;
                }
            } else {
                const float* pb = planes + (size_t)m * NCOMP * GRES * GRES;
                for (int c = 0; c < NCOMP; ++c) {
                    const float* pc = pb + (size_t)c * GRES * GRES + (size_t)y0 * GRES + x0;
                    const float* lc = lines + ((size_t)m * NCOMP + c) * GRES + z0;
                    float pf = pc[0] * w00 + pc[1] * w01 + pc[GRES] * w10 + pc[GRES + 1] * w11;
                    float lf = lc[0] * lw0 + lc[1] * lw1;
                    dst[c] = (_Float16)(pf * lf);
                }
            }
        } else {
            // embed: new k 108..110 = xyz; 111+d*3+f = sin(x_d*2^f); 120+d*3+f = cos
            _Float16* e = &mlp_lds[p * S_IN];
            e[108] = (_Float16)X; e[109] = (_Float16)Y; e[110] = (_Float16)Z;
            const float v3[3] = {X, Y, Z};
            #pragma unroll
            for (int d = 0; d < 3; ++d) {
                float f = 1.f;
                #pragma unroll
                for (int q = 0; q < 3; ++q) {
                    const float a = v3[d] * f;
                    e[111 + d * 3 + q] = (_Float16)__sinf(a);
                    e[120 + d * 3 + q] = (_Float16)__cosf(a);
                    f *= 2.f;
                }
            }
            e[129] = (_Float16)0.f;
            #pragma unroll
            for (int k = 130; k < IN_PAD; k += 2)
                *(half2v*)&e[k] = (half2v){(_Float16)0.f, (_Float16)0.f};
        }
    }
    __syncthreads();

    const int lane = tid & 63;
    const int wv   = tid >> 6;      // wave 0..3
    const int l15  = lane & 15;
    const int quad = lane >> 4;

    // ---------------- layer 1: [64x160] @ [160x256] -> h -------------------
    floatx4 acc1[4][4];
    #pragma unroll
    for (int mt = 0; mt < 4; ++mt)
        #pragma unroll
        for (int nt = 0; nt < 4; ++nt)
            acc1[mt][nt] = (floatx4){0.f, 0.f, 0.f, 0.f};

    #pragma unroll
    for (int s = 0; s < 5; ++s) {
        half8 a[4], b[4];
        #pragma unroll
        for (int mt = 0; mt < 4; ++mt)
            a[mt] = *(const half8*)&mlp_lds[(mt * 16 + l15) * S_IN + s * 32 + quad * 8];
        #pragma unroll
        for (int nt = 0; nt < 4; ++nt)
            b[nt] = *(const half8*)&w1s[((size_t)(s * 4 + quad) * 256 + wv * 64 + nt * 16 + l15) * 8];
        #pragma unroll
        for (int mt = 0; mt < 4; ++mt)
            #pragma unroll
            for (int nt = 0; nt < 4; ++nt)
                acc1[mt][nt] = __builtin_amdgcn_mfma_f32_16x16x32_f16(a[mt], b[nt], acc1[mt][nt], 0, 0, 0);
    }
    // epilogue: softplus(100z)/100 via v_exp/v_log, write h (f16) to LDS [m][k]
    #pragma unroll
    for (int nt = 0; nt < 4; ++nt) {
        const int n = wv * 64 + nt * 16 + l15;
        const float bias = b1[n];
        #pragma unroll
        for (int mt = 0; mt < 4; ++mt) {
            #pragma unroll
            for (int r = 0; r < 4; ++r) {
                const float z = 100.f * (acc1[mt][nt][r] + bias);
                h_lds[(mt * 16 + quad * 4 + r) * S_H + n] = (_Float16)(softplus100(z) * 0.01f);
            }
        }
    }
    __syncthreads();

    // ---------------- layer 2: [64x256] @ [256x144] -> out -----------------
    floatx4 acc2[9];
    #pragma unroll
    for (int nt = 0; nt < 9; ++nt) acc2[nt] = (floatx4){0.f, 0.f, 0.f, 0.f};

    #pragma unroll
    for (int s = 0; s < 8; ++s) {
        const half8 a = *(const half8*)&h_lds[(wv * 16 + l15) * S_H + s * 32 + quad * 8];
        #pragma unroll
        for (int nt = 0; nt < 9; ++nt) {
            const half8 b = *(const half8*)&w2s[((size_t)(s * 4 + quad) * 144 + nt * 16 + l15) * 8];
            acc2[nt] = __builtin_amdgcn_mfma_f32_16x16x32_f16(a, b, acc2[nt], 0, 0, 0);
        }
    }
    const int m_lo = wv * 16 + quad * 4;
    #pragma unroll
    for (int nt = 0; nt < 9; ++nt) {
        const int n = nt * 16 + l15;
        if (n < OUT_CH) {
            const float bias = b2[n];
            #pragma unroll
            for (int r = 0; r < 4; ++r) {
                const size_t gm = (size_t)blk * TILE_M + m_lo + r;
                out[gm * OUT_CH + n] = acc2[nt][r] + bias;
            }
        }
    }
}

// ---- launch ---------------------------------------------------------------

extern "C" void kernel_launch(void* const* d_in, const int* in_sizes, int n_in,
                              void* d_out, int out_size, void* d_ws, size_t ws_size,
                              hipStream_t stream) {
    const float* xyz    = (const float*)d_in[0];
    const float* planes = (const float*)d_in[1];
    const float* lines  = (const float*)d_in[2];
    const float* w1     = (const float*)d_in[3];
    const float* b1     = (const float*)d_in[4];
    const float* w2     = (const float*)d_in[5];
    const float* b2     = (const float*)d_in[6];
    float* out = (float*)d_out;
    char* ws = (char*)d_ws;

    _Float16* w1s  = (_Float16*)(ws + OFF_W1S);
    _Float16* w2s  = (_Float16*)(ws + OFF_W2S);
    _Float16* pl_t = (_Float16*)(ws + OFF_PLT);
    _Float16* l_t  = (_Float16*)(ws + OFF_LT);

    const bool fast = (ws_size >= WS_NEED_FAST);

    prep_small_k<<<NB_W1 + NB_W2 + NB_L, 256, 0, stream>>>(w1, w2, lines, w1s, w2s, l_t);

    if (fast) {
        prep_planes_k<<<(3 * GRES * GRES + 255) / 256, 256, 0, stream>>>(planes, pl_t);
        tsdf_fused_k<true><<<NPTS / TILE_M, 256, 0, stream>>>(
            xyz, planes, lines, pl_t, l_t, w1s, w2s, b1, b2, out);
    } else {
        tsdf_fused_k<false><<<NPTS / TILE_M, 256, 0, stream>>>(
            xyz, planes, lines, pl_t, l_t, w1s, w2s, b1, b2, out);
    }
}